// Round 5
// baseline (219.471 us; speedup 1.0000x reference)
//
#include <hip/hip_runtime.h>
#include <hip/hip_bf16.h>
#include <math.h>

#define B 8192
#define D 128
#define NCHUNK 32
#define CPC (B / NCHUNK)      /* 256 cols per chunk */
#define NCG (CPC / 16)        /* 16 col-groups per chunk */
#define RPB 128               /* rows per block: 4 waves x 32 */
#define MARGIN 1.0f

typedef short short8 __attribute__((ext_vector_type(8)));
typedef float f32x4 __attribute__((ext_vector_type(4)));

// ws layout: sqn [B] f32 | ppos [NCHUNK*B] f32 | pneg [NCHUNK*B] f32 | Xh [B*256] ushort
// Xh row layout (plain, no swizzle): granule g (8 ushorts): hi at g=0..15, lo at g=16..31.

__device__ inline ushort f2bf(float f) {
    __hip_bfloat16 h = __float2bfloat16(f);
    ushort u; __builtin_memcpy(&u, &h, 2); return u;
}
__device__ inline float bf2f(ushort u) {
    unsigned int i = ((unsigned)u) << 16; float f; __builtin_memcpy(&f, &i, 4); return f;
}

// Fused prep: bf16 hi/lo split (plain layout), row sq-norms, out zero.
__global__ void mmcl_prep_kernel(const float* __restrict__ X,
                                 ushort* __restrict__ Xh,
                                 float* __restrict__ sqn,
                                 float* __restrict__ out) {
    const int t  = blockIdx.x * 256 + threadIdx.x;
    const int r  = t >> 4;
    const int kg = t & 15;
    const float4 v0 = *(const float4*)(X + (size_t)r * D + kg * 8);
    const float4 v1 = *(const float4*)(X + (size_t)r * D + kg * 8 + 4);
    const float xs[8] = {v0.x, v0.y, v0.z, v0.w, v1.x, v1.y, v1.z, v1.w};

    float s = 0.f;
    #pragma unroll
    for (int i = 0; i < 8; ++i) s = fmaf(xs[i], xs[i], s);
    #pragma unroll
    for (int off = 1; off < 16; off <<= 1) s += __shfl_xor(s, off);
    if (kg == 0) sqn[r] = s;

    short8 hv, lv;
    #pragma unroll
    for (int i = 0; i < 8; ++i) {
        const float x = xs[i];
        const ushort h = f2bf(x);
        hv[i] = (short)h;
        lv[i] = (short)f2bf(x - bf2f(h));
    }
    ushort* rp = Xh + (size_t)r * 256;
    *(short8*)(rp + (kg << 3))         = hv;
    *(short8*)(rp + ((16 + kg) << 3))  = lv;

    if (t == 0) *out = 0.0f;
}

__global__ __launch_bounds__(256, 3) void mmcl_mfma_kernel(
    const ushort* __restrict__ Xh, const float* __restrict__ sqn,
    const int* __restrict__ lab,
    float* __restrict__ ppos, float* __restrict__ pneg)
{
    const int tid  = threadIdx.x;
    const int w    = tid >> 6;
    const int lane = tid & 63;
    const int lhi  = lane >> 4;
    const int llo  = lane & 15;
    const int R    = blockIdx.x * RPB + w * 32;   // this wave's 32 rows
    const int C0   = blockIdx.y * CPC;
    const int chnk = blockIdx.y;

    // A fragments: rows R + m*16 + llo (m=0,1), full K=128 hi+lo in registers (64 VGPR)
    short8 a_hi[2][4], a_lo[2][4];
    #pragma unroll
    for (int m = 0; m < 2; ++m) {
        const ushort* rp = Xh + (size_t)(R + m * 16 + llo) * 256;
        #pragma unroll
        for (int kf = 0; kf < 4; ++kf) {
            const int g = kf * 4 + lhi;
            a_hi[m][kf] = *(const short8*)(rp + (g << 3));
            a_lo[m][kf] = *(const short8*)(rp + ((16 + g) << 3));
        }
    }

    int labR[2][4];   // rows R + m*16 + lhi*4 + r  (C/D layout: col=lane&15, row=lhi*4+reg)
    #pragma unroll
    for (int m = 0; m < 2; ++m)
        #pragma unroll
        for (int r = 0; r < 4; ++r)
            labR[m][r] = lab[R + m * 16 + lhi * 4 + r];

    float minpos[2][4], maxneg[2][4];
    #pragma unroll
    for (int m = 0; m < 2; ++m)
        #pragma unroll
        for (int r = 0; r < 4; ++r) { minpos[m][r] = INFINITY; maxneg[m][r] = -INFINITY; }

    // col metadata prefetch (depth 1)
    float sq_pf = sqn[C0 + llo];
    int   lc_pf = lab[C0 + llo];

    for (int cg = 0; cg < NCG; ++cg) {
        const int c = C0 + cg * 16;
        const float sq_c = sq_pf;
        const int   lc   = lc_pf;
        if (cg + 1 < NCG) {
            sq_pf = sqn[c + 16 + llo];
            lc_pf = lab[c + 16 + llo];
        }

        // B fragments straight from global (L1/L2): col = c + llo, granule kf*4+lhi
        const ushort* bp = Xh + (size_t)(c + llo) * 256;
        f32x4 acc[2][2];   // [m][kf&1] -> 4 independent MFMA chains
        #pragma unroll
        for (int m = 0; m < 2; ++m) {
            acc[m][0] = (f32x4){0.f, 0.f, 0.f, 0.f};
            acc[m][1] = (f32x4){0.f, 0.f, 0.f, 0.f};
        }

        __builtin_amdgcn_s_setprio(1);
        #pragma unroll
        for (int kf = 0; kf < 4; ++kf) {
            const int g = kf * 4 + lhi;
            const short8 b_hi = *(const short8*)(bp + (g << 3));
            const short8 b_lo = *(const short8*)(bp + ((16 + g) << 3));
            const int p = kf & 1;
            #pragma unroll
            for (int m = 0; m < 2; ++m) {
                acc[m][p] = __builtin_amdgcn_mfma_f32_16x16x32_bf16(a_hi[m][kf], b_hi, acc[m][p], 0, 0, 0);
                acc[m][p] = __builtin_amdgcn_mfma_f32_16x16x32_bf16(a_hi[m][kf], b_lo, acc[m][p], 0, 0, 0);
                acc[m][p] = __builtin_amdgcn_mfma_f32_16x16x32_bf16(a_lo[m][kf], b_hi, acc[m][p], 0, 0, 0);
            }
        }
        __builtin_amdgcn_s_setprio(0);

        const int col = c + llo;
        const bool hd = (c < R + 32) && (c + 16 > R);   // this cg touches the diagonal
        if (hd) {
            #pragma unroll
            for (int m = 0; m < 2; ++m) {
                const int rowb = R + m * 16 + lhi * 4;
                #pragma unroll
                for (int r = 0; r < 4; ++r) {
                    float v = acc[m][0][r] + acc[m][1][r];
                    v = fmaf(-2.0f, v, sq_c);
                    const bool same = (labR[m][r] == lc);
                    const bool diag = (rowb + r == col);
                    const float vp = (same && !diag) ? v : INFINITY;
                    const float vn = same ? -INFINITY : v;
                    minpos[m][r] = fminf(minpos[m][r], vp);
                    maxneg[m][r] = fmaxf(maxneg[m][r], vn);
                }
            }
        } else {
            #pragma unroll
            for (int m = 0; m < 2; ++m) {
                #pragma unroll
                for (int r = 0; r < 4; ++r) {
                    float v = acc[m][0][r] + acc[m][1][r];
                    v = fmaf(-2.0f, v, sq_c);
                    const bool same = (labR[m][r] == lc);
                    const float vp = same ? v : INFINITY;
                    const float vn = same ? -INFINITY : v;
                    minpos[m][r] = fminf(minpos[m][r], vp);
                    maxneg[m][r] = fmaxf(maxneg[m][r], vn);
                }
            }
        }
    }

    // reduce across the 16 llo lanes (cols of this wave's groups), store chunk-major partials
    #pragma unroll
    for (int m = 0; m < 2; ++m)
        #pragma unroll
        for (int r = 0; r < 4; ++r) {
            float mp = minpos[m][r], mn = maxneg[m][r];
            #pragma unroll
            for (int off = 1; off < 16; off <<= 1) {
                mp = fminf(mp, __shfl_xor(mp, off));
                mn = fmaxf(mn, __shfl_xor(mn, off));
            }
            if (llo == 0) {
                const int row = R + m * 16 + lhi * 4 + r;
                ppos[(size_t)chnk * B + row] = mp;   // contiguous per block: no write amplification
                pneg[(size_t)chnk * B + row] = mn;
            }
        }
}

__global__ void mmcl_final_kernel(const float* __restrict__ sqn,
                                  const float* __restrict__ ppos,
                                  const float* __restrict__ pneg,
                                  float* __restrict__ out)
{
    const int row = blockIdx.x * 256 + threadIdx.x;
    float mp = INFINITY, mn = -INFINITY;
    #pragma unroll
    for (int c = 0; c < NCHUNK; ++c) {
        mp = fminf(mp, ppos[(size_t)c * B + row]);
        mn = fmaxf(mn, pneg[(size_t)c * B + row]);
    }
    const float sq  = sqn[row];
    const float pos = isinf(mp) ? INFINITY : sqrtf(fmaxf(sq + mp, 0.f));
    const float neg = (mn == -INFINITY) ? -INFINITY : sqrtf(fmaxf(sq + mn, 0.f));
    const float term = fmaxf(pos - neg + MARGIN, 0.f);

    float s = term;
    #pragma unroll
    for (int off = 32; off; off >>= 1) s += __shfl_down(s, off);
    __shared__ float wsum[4];
    const int wave = threadIdx.x >> 6, lane = threadIdx.x & 63;
    if (lane == 0) wsum[wave] = s;
    __syncthreads();
    if (threadIdx.x == 0)
        atomicAdd(out, (wsum[0] + wsum[1] + wsum[2] + wsum[3]) * (1.0f / B));
}

extern "C" void kernel_launch(void* const* d_in, const int* in_sizes, int n_in,
                              void* d_out, int out_size, void* d_ws, size_t ws_size,
                              hipStream_t stream) {
    (void)in_sizes; (void)n_in; (void)out_size; (void)ws_size;
    const float* X   = (const float*)d_in[0];
    const int*   lab = (const int*)d_in[1];
    float* out = (float*)d_out;

    float*  sqn  = (float*)d_ws;
    float*  ppos = sqn + B;
    float*  pneg = ppos + (size_t)NCHUNK * B;
    ushort* Xh   = (ushort*)(pneg + (size_t)NCHUNK * B);

    mmcl_prep_kernel<<<(B * 16) / 256, 256, 0, stream>>>(X, Xh, sqn, out);
    mmcl_mfma_kernel<<<dim3(B / RPB, NCHUNK), 256, 0, stream>>>(Xh, sqn, lab, ppos, pneg);
    mmcl_final_kernel<<<B / 256, 256, 0, stream>>>(sqn, ppos, pneg, out);
}

// Round 7
// 153.477 us; speedup vs baseline: 1.4300x; 1.4300x over previous
//
#include <hip/hip_runtime.h>
#include <hip/hip_bf16.h>
#include <math.h>

#define B 8192
#define D 128
#define NCHUNK 32
#define CPC (B / NCHUNK)      /* 256 cols per chunk */
#define CT 32                 /* cols per LDS tile */
#define NCT (CPC / CT)        /* 8 tiles per chunk */
#define RPB 128               /* rows per block: 4 waves x 32 */
#define MARGIN 1.0f

typedef short short8 __attribute__((ext_vector_type(8)));
typedef float f32x4 __attribute__((ext_vector_type(4)));

// ws layout: sqn [B] f32 | ppos [NCHUNK*B] f32 | pneg [NCHUNK*B] f32 | Xh [B*256] ushort
// Xh row: 32 granules of 8 ushorts; granule g stored at slot (g ^ (row&7)); hi g=0..15, lo g=16..31.

__device__ inline ushort f2bf(float f) {
    __hip_bfloat16 h = __float2bfloat16(f);
    ushort u; __builtin_memcpy(&u, &h, 2); return u;
}
__device__ inline float bf2f(ushort u) {
    unsigned int i = ((unsigned)u) << 16; float f; __builtin_memcpy(&f, &i, 4); return f;
}

__device__ inline void gload_lds16(const void* gsrc, void* ldst) {
    __builtin_amdgcn_global_load_lds(
        (const __attribute__((address_space(1))) unsigned int*)gsrc,
        (__attribute__((address_space(3))) unsigned int*)ldst,
        16, 0, 0);
}

// Fused prep: bf16 hi/lo split (granule-swizzled by row&7), row sq-norms, out zero.
__global__ void mmcl_prep_kernel(const float* __restrict__ X,
                                 ushort* __restrict__ Xh,
                                 float* __restrict__ sqn,
                                 float* __restrict__ out) {
    const int t  = blockIdx.x * 256 + threadIdx.x;
    const int r  = t >> 4;
    const int kg = t & 15;
    const float4 v0 = *(const float4*)(X + (size_t)r * D + kg * 8);
    const float4 v1 = *(const float4*)(X + (size_t)r * D + kg * 8 + 4);
    const float xs[8] = {v0.x, v0.y, v0.z, v0.w, v1.x, v1.y, v1.z, v1.w};

    float s = 0.f;
    #pragma unroll
    for (int i = 0; i < 8; ++i) s = fmaf(xs[i], xs[i], s);
    #pragma unroll
    for (int off = 1; off < 16; off <<= 1) s += __shfl_xor(s, off);
    if (kg == 0) sqn[r] = s;

    short8 hv, lv;
    #pragma unroll
    for (int i = 0; i < 8; ++i) {
        const float x = xs[i];
        const ushort h = f2bf(x);
        hv[i] = (short)h;
        lv[i] = (short)f2bf(x - bf2f(h));
    }
    const int sw = r & 7;
    ushort* rp = Xh + (size_t)r * 256;
    *(short8*)(rp + ((kg ^ sw) << 3))        = hv;
    *(short8*)(rp + (((16 + kg) ^ sw) << 3)) = lv;

    if (t == 0) *out = 0.0f;
}

__global__ __launch_bounds__(256, 4) void mmcl_mfma_kernel(
    const ushort* __restrict__ Xh, const float* __restrict__ sqn,
    const int* __restrict__ lab,
    float* __restrict__ ppos, float* __restrict__ pneg)
{
    __shared__ ushort lds[2][CT * 256];   // 2 x 16KB double-buffered col tiles (swizzled layout)
    __shared__ float  smeta_sq[CPC];      // col sq-norms for this chunk
    __shared__ int    smeta_lab[CPC];     // col labels for this chunk

    const int tid  = threadIdx.x;
    const int lane = tid & 63;
    const int lhi  = lane >> 4;
    const int llo  = lane & 15;
    const int R    = blockIdx.x * RPB + (tid >> 6) * 32;   // this wave's 32 rows
    const int C0   = blockIdx.y * CPC;
    const int chnk = blockIdx.y;

    // stage col metadata once (256 threads == CPC cols); first barrier publishes it
    smeta_sq[tid]  = sqn[C0 + tid];
    smeta_lab[tid] = lab[C0 + tid];

    // A fragments: rows R + m*16 + llo (m=0,1), full K=128 hi+lo in registers (64 VGPR)
    short8 a_hi[2][4], a_lo[2][4];
    #pragma unroll
    for (int m = 0; m < 2; ++m) {
        const int row = R + m * 16 + llo;
        const int sw = row & 7;
        const ushort* rp = Xh + (size_t)row * 256;
        #pragma unroll
        for (int kf = 0; kf < 4; ++kf) {
            const int g = kf * 4 + lhi;
            a_hi[m][kf] = *(const short8*)(rp + ((g ^ sw) << 3));
            a_lo[m][kf] = *(const short8*)(rp + (((16 + g) ^ sw) << 3));
        }
    }

    // packed byte labels for this lane's 8 C-rows (labels < 100 fit a byte)
    unsigned labP[2];
    #pragma unroll
    for (int m = 0; m < 2; ++m) {
        const int rowb = R + m * 16 + lhi * 4;
        labP[m] = (unsigned)(lab[rowb] & 0xFF)
                | ((unsigned)(lab[rowb + 1] & 0xFF) << 8)
                | ((unsigned)(lab[rowb + 2] & 0xFF) << 16)
                | ((unsigned)(lab[rowb + 3] & 0xFF) << 24);
    }

    float minpos[2][4], maxneg[2][4];
    #pragma unroll
    for (int m = 0; m < 2; ++m)
        #pragma unroll
        for (int r = 0; r < 4; ++r) { minpos[m][r] = INFINITY; maxneg[m][r] = -INFINITY; }

    // stage tile t (16KB contiguous, swizzle preserved): 256 threads x 4 x 16B
    auto stage = [&](int buf, int t) {
        const char* g = (const char*)(Xh + (size_t)(C0 + t * CT) * 256) + tid * 16;
        char* l = (char*)&lds[buf][0] + tid * 16;
        #pragma unroll
        for (int k = 0; k < 4; ++k)
            gload_lds16(g + k * 4096, l + k * 4096);
    };

    stage(0, 0);

    for (int t = 0; t < NCT; ++t) {
        const int cur = t & 1;
        __syncthreads();                 // drains stage(cur); all waves done reading cur^1
        if (t + 1 < NCT) stage(cur ^ 1, t + 1);

        const int colbase = C0 + t * CT;

        #pragma unroll
        for (int n = 0; n < 2; ++n) {
            const int cl = n * 16 + llo;     // local col; (global col)&7 == cl&7
            const int sw = cl & 7;
            const ushort* bp = &lds[cur][cl * 256];
            f32x4 acc[2];
            acc[0] = (f32x4){0.f, 0.f, 0.f, 0.f};
            acc[1] = (f32x4){0.f, 0.f, 0.f, 0.f};

            __builtin_amdgcn_s_setprio(1);
            #pragma unroll
            for (int kf = 0; kf < 4; ++kf) {
                const int g = kf * 4 + lhi;
                const short8 b_hi = *(const short8*)(bp + ((g ^ sw) << 3));
                const short8 b_lo = *(const short8*)(bp + (((16 + g) ^ sw) << 3));
                #pragma unroll
                for (int m = 0; m < 2; ++m) {
                    acc[m] = __builtin_amdgcn_mfma_f32_16x16x32_bf16(a_hi[m][kf], b_hi, acc[m], 0, 0, 0);
                    acc[m] = __builtin_amdgcn_mfma_f32_16x16x32_bf16(a_hi[m][kf], b_lo, acc[m], 0, 0, 0);
                    acc[m] = __builtin_amdgcn_mfma_f32_16x16x32_bf16(a_lo[m][kf], b_hi, acc[m], 0, 0, 0);
                }
            }
            __builtin_amdgcn_s_setprio(0);

            const int col   = colbase + cl;
            const float sqc = smeta_sq[t * CT + cl];
            const int   lc  = smeta_lab[t * CT + cl];
            const bool  hd  = (colbase + n * 16 + 16 > R) && (colbase + n * 16 < R + 32);

            if (hd) {
                #pragma unroll
                for (int m = 0; m < 2; ++m) {
                    const int rowb = R + m * 16 + lhi * 4;
                    #pragma unroll
                    for (int r = 0; r < 4; ++r) {
                        const float v = fmaf(-2.0f, acc[m][r], sqc);
                        const bool same = (int)((labP[m] >> (8 * r)) & 0xFF) == lc;
                        const bool diag = (rowb + r == col);
                        const float vp = (same && !diag) ? v : INFINITY;
                        const float vn = same ? -INFINITY : v;
                        minpos[m][r] = fminf(minpos[m][r], vp);
                        maxneg[m][r] = fmaxf(maxneg[m][r], vn);
                    }
                }
            } else {
                #pragma unroll
                for (int m = 0; m < 2; ++m) {
                    #pragma unroll
                    for (int r = 0; r < 4; ++r) {
                        const float v = fmaf(-2.0f, acc[m][r], sqc);
                        const bool same = (int)((labP[m] >> (8 * r)) & 0xFF) == lc;
                        const float vp = same ? v : INFINITY;
                        const float vn = same ? -INFINITY : v;
                        minpos[m][r] = fminf(minpos[m][r], vp);
                        maxneg[m][r] = fmaxf(maxneg[m][r], vn);
                    }
                }
            }
        }
    }

    // reduce across the 16 llo lanes (cols), store chunk-major contiguous partials
    #pragma unroll
    for (int m = 0; m < 2; ++m)
        #pragma unroll
        for (int r = 0; r < 4; ++r) {
            float mp = minpos[m][r], mn = maxneg[m][r];
            #pragma unroll
            for (int off = 1; off < 16; off <<= 1) {
                mp = fminf(mp, __shfl_xor(mp, off));
                mn = fmaxf(mn, __shfl_xor(mn, off));
            }
            if (llo == 0) {
                const int row = R + m * 16 + lhi * 4 + r;
                ppos[(size_t)chnk * B + row] = mp;
                pneg[(size_t)chnk * B + row] = mn;
            }
        }
}

__global__ void mmcl_final_kernel(const float* __restrict__ sqn,
                                  const float* __restrict__ ppos,
                                  const float* __restrict__ pneg,
                                  float* __restrict__ out)
{
    const int row = blockIdx.x * 256 + threadIdx.x;
    float mp = INFINITY, mn = -INFINITY;
    #pragma unroll
    for (int c = 0; c < NCHUNK; ++c) {
        mp = fminf(mp, ppos[(size_t)c * B + row]);
        mn = fmaxf(mn, pneg[(size_t)c * B + row]);
    }
    const float sq  = sqn[row];
    const float pos = isinf(mp) ? INFINITY : sqrtf(fmaxf(sq + mp, 0.f));
    const float neg = (mn == -INFINITY) ? -INFINITY : sqrtf(fmaxf(sq + mn, 0.f));
    const float term = fmaxf(pos - neg + MARGIN, 0.f);

    float s = term;
    #pragma unroll
    for (int off = 32; off; off >>= 1) s += __shfl_down(s, off);
    __shared__ float wsum[4];
    const int wave = threadIdx.x >> 6, lane = threadIdx.x & 63;
    if (lane == 0) wsum[wave] = s;
    __syncthreads();
    if (threadIdx.x == 0)
        atomicAdd(out, (wsum[0] + wsum[1] + wsum[2] + wsum[3]) * (1.0f / B));
}

extern "C" void kernel_launch(void* const* d_in, const int* in_sizes, int n_in,
                              void* d_out, int out_size, void* d_ws, size_t ws_size,
                              hipStream_t stream) {
    (void)in_sizes; (void)n_in; (void)out_size; (void)ws_size;
    const float* X   = (const float*)d_in[0];
    const int*   lab = (const int*)d_in[1];
    float* out = (float*)d_out;

    float*  sqn  = (float*)d_ws;
    float*  ppos = sqn + B;
    float*  pneg = ppos + (size_t)NCHUNK * B;
    ushort* Xh   = (ushort*)(pneg + (size_t)NCHUNK * B);

    mmcl_prep_kernel<<<(B * 16) / 256, 256, 0, stream>>>(X, Xh, sqn, out);
    mmcl_mfma_kernel<<<dim3(B / RPB, NCHUNK), 256, 0, stream>>>(Xh, sqn, lab, ppos, pneg);
    mmcl_final_kernel<<<B / 256, 256, 0, stream>>>(sqn, ppos, pneg, out);
}

// Round 8
// 121.435 us; speedup vs baseline: 1.8073x; 1.2639x over previous
//
#include <hip/hip_runtime.h>
#include <hip/hip_bf16.h>
#include <math.h>

#define B 8192
#define D 128
#define NCHUNK 32
#define CPC (B / NCHUNK)      /* 256 cols per chunk */
#define CT 32                 /* cols per LDS tile */
#define NCT (CPC / CT)        /* 8 tiles per chunk */
#define RPB 128               /* rows per block: 4 waves x 32 */
#define MARGIN 1.0f

typedef short short8 __attribute__((ext_vector_type(8)));
typedef float f32x4 __attribute__((ext_vector_type(4)));

// ws layout: sqn [B] f32 | ppos [NCHUNK*B] f32 | pneg [NCHUNK*B] f32 | Xh [B*256] ushort
// Xh row: 32 granules of 8 ushorts; granule g stored at slot (g ^ (row&7)); hi g=0..15, lo g=16..31.

__device__ inline ushort f2bf(float f) {
    __hip_bfloat16 h = __float2bfloat16(f);
    ushort u; __builtin_memcpy(&u, &h, 2); return u;
}
__device__ inline float bf2f(ushort u) {
    unsigned int i = ((unsigned)u) << 16; float f; __builtin_memcpy(&f, &i, 4); return f;
}

__device__ inline void gload_lds16(const void* gsrc, void* ldst) {
    __builtin_amdgcn_global_load_lds(
        (const __attribute__((address_space(1))) unsigned int*)gsrc,
        (__attribute__((address_space(3))) unsigned int*)ldst,
        16, 0, 0);
}

// Fused prep: bf16 hi/lo split (granule-swizzled by row&7), row sq-norms, out zero.
__global__ void mmcl_prep_kernel(const float* __restrict__ X,
                                 ushort* __restrict__ Xh,
                                 float* __restrict__ sqn,
                                 float* __restrict__ out) {
    const int t  = blockIdx.x * 256 + threadIdx.x;
    const int r  = t >> 4;
    const int kg = t & 15;
    const float4 v0 = *(const float4*)(X + (size_t)r * D + kg * 8);
    const float4 v1 = *(const float4*)(X + (size_t)r * D + kg * 8 + 4);
    const float xs[8] = {v0.x, v0.y, v0.z, v0.w, v1.x, v1.y, v1.z, v1.w};

    float s = 0.f;
    #pragma unroll
    for (int i = 0; i < 8; ++i) s = fmaf(xs[i], xs[i], s);
    #pragma unroll
    for (int off = 1; off < 16; off <<= 1) s += __shfl_xor(s, off);
    if (kg == 0) sqn[r] = s;

    short8 hv, lv;
    #pragma unroll
    for (int i = 0; i < 8; ++i) {
        const float x = xs[i];
        const ushort h = f2bf(x);
        hv[i] = (short)h;
        lv[i] = (short)f2bf(x - bf2f(h));
    }
    const int sw = r & 7;
    ushort* rp = Xh + (size_t)r * 256;
    *(short8*)(rp + ((kg ^ sw) << 3))        = hv;
    *(short8*)(rp + (((16 + kg) ^ sw) << 3)) = lv;

    if (t == 0) *out = 0.0f;
}

__global__ __launch_bounds__(256, 3) void mmcl_mfma_kernel(
    const ushort* __restrict__ Xh, const float* __restrict__ sqn,
    const int* __restrict__ lab,
    float* __restrict__ ppos, float* __restrict__ pneg)
{
    __shared__ ushort lds[2][CT * 256];   // 2 x 16KB double-buffered col tiles (swizzled layout)
    __shared__ float  smeta_sq[CPC];      // col sq-norms for this chunk
    __shared__ int    smeta_lab[CPC];     // col labels for this chunk

    const int tid  = threadIdx.x;
    const int lane = tid & 63;
    const int lhi  = lane >> 4;
    const int llo  = lane & 15;
    const int R    = blockIdx.x * RPB + (tid >> 6) * 32;   // this wave's 32 rows
    const int C0   = blockIdx.y * CPC;
    const int chnk = blockIdx.y;

    // stage col metadata once (256 threads == CPC cols); first barrier publishes it
    smeta_sq[tid]  = sqn[C0 + tid];
    smeta_lab[tid] = lab[C0 + tid];

    // A fragments: rows R + m*16 + llo (m=0,1), full K=128 hi+lo in registers (64 VGPR).
    // asm pins force true residency (round-7 lesson: compiler remats these otherwise).
    short8 a_hi[2][4], a_lo[2][4];
    #pragma unroll
    for (int m = 0; m < 2; ++m) {
        const int row = R + m * 16 + llo;
        const int sw = row & 7;
        const ushort* rp = Xh + (size_t)row * 256;
        #pragma unroll
        for (int kf = 0; kf < 4; ++kf) {
            const int g = kf * 4 + lhi;
            a_hi[m][kf] = *(const short8*)(rp + ((g ^ sw) << 3));
            a_lo[m][kf] = *(const short8*)(rp + (((16 + g) ^ sw) << 3));
            asm volatile("" : "+v"(a_hi[m][kf]));
            asm volatile("" : "+v"(a_lo[m][kf]));
        }
    }

    // packed byte labels for this lane's 8 C-rows (labels < 100 fit a byte)
    unsigned labP[2];
    #pragma unroll
    for (int m = 0; m < 2; ++m) {
        const int rowb = R + m * 16 + lhi * 4;
        labP[m] = (unsigned)(lab[rowb] & 0xFF)
                | ((unsigned)(lab[rowb + 1] & 0xFF) << 8)
                | ((unsigned)(lab[rowb + 2] & 0xFF) << 16)
                | ((unsigned)(lab[rowb + 3] & 0xFF) << 24);
    }

    float minpos[2][4], maxneg[2][4];
    #pragma unroll
    for (int m = 0; m < 2; ++m)
        #pragma unroll
        for (int r = 0; r < 4; ++r) { minpos[m][r] = INFINITY; maxneg[m][r] = -INFINITY; }

    // stage tile t (16KB contiguous, swizzle preserved): 256 threads x 4 x 16B
    auto stage = [&](int buf, int t) {
        const char* g = (const char*)(Xh + (size_t)(C0 + t * CT) * 256) + tid * 16;
        char* l = (char*)&lds[buf][0] + tid * 16;
        #pragma unroll
        for (int k = 0; k < 4; ++k)
            gload_lds16(g + k * 4096, l + k * 4096);
    };

    stage(0, 0);

    for (int t = 0; t < NCT; ++t) {
        const int cur = t & 1;
        __syncthreads();                 // drains stage(cur); all waves done reading cur^1
        if (t + 1 < NCT) stage(cur ^ 1, t + 1);

        const int colbase = C0 + t * CT;

        #pragma unroll
        for (int n = 0; n < 2; ++n) {
            const int cl = n * 16 + llo;     // local col; (global col)&7 == cl&7
            const int sw = cl & 7;
            const ushort* bp = &lds[cur][cl * 256];
            f32x4 acc[2];
            acc[0] = (f32x4){0.f, 0.f, 0.f, 0.f};
            acc[1] = (f32x4){0.f, 0.f, 0.f, 0.f};

            __builtin_amdgcn_s_setprio(1);
            #pragma unroll
            for (int kf = 0; kf < 4; ++kf) {
                const int g = kf * 4 + lhi;
                const short8 b_hi = *(const short8*)(bp + ((g ^ sw) << 3));
                const short8 b_lo = *(const short8*)(bp + (((16 + g) ^ sw) << 3));
                #pragma unroll
                for (int m = 0; m < 2; ++m) {
                    acc[m] = __builtin_amdgcn_mfma_f32_16x16x32_bf16(a_hi[m][kf], b_hi, acc[m], 0, 0, 0);
                    acc[m] = __builtin_amdgcn_mfma_f32_16x16x32_bf16(a_hi[m][kf], b_lo, acc[m], 0, 0, 0);
                    acc[m] = __builtin_amdgcn_mfma_f32_16x16x32_bf16(a_lo[m][kf], b_hi, acc[m], 0, 0, 0);
                }
            }
            __builtin_amdgcn_s_setprio(0);

            const int col   = colbase + cl;
            const float sqc = smeta_sq[t * CT + cl];
            const int   lc  = smeta_lab[t * CT + cl];
            const bool  hd  = (colbase + n * 16 + 16 > R) && (colbase + n * 16 < R + 32);

            if (hd) {
                #pragma unroll
                for (int m = 0; m < 2; ++m) {
                    const int rowb = R + m * 16 + lhi * 4;
                    #pragma unroll
                    for (int r = 0; r < 4; ++r) {
                        const float v = fmaf(-2.0f, acc[m][r], sqc);
                        const bool same = (int)((labP[m] >> (8 * r)) & 0xFF) == lc;
                        const bool diag = (rowb + r == col);
                        const float vp = (same && !diag) ? v : INFINITY;
                        const float vn = same ? -INFINITY : v;
                        minpos[m][r] = fminf(minpos[m][r], vp);
                        maxneg[m][r] = fmaxf(maxneg[m][r], vn);
                    }
                }
            } else {
                #pragma unroll
                for (int m = 0; m < 2; ++m) {
                    #pragma unroll
                    for (int r = 0; r < 4; ++r) {
                        const float v = fmaf(-2.0f, acc[m][r], sqc);
                        const bool same = (int)((labP[m] >> (8 * r)) & 0xFF) == lc;
                        const float vp = same ? v : INFINITY;
                        const float vn = same ? -INFINITY : v;
                        minpos[m][r] = fminf(minpos[m][r], vp);
                        maxneg[m][r] = fmaxf(maxneg[m][r], vn);
                    }
                }
            }
        }
    }

    // reduce across the 16 llo lanes (cols), store chunk-major contiguous partials
    #pragma unroll
    for (int m = 0; m < 2; ++m)
        #pragma unroll
        for (int r = 0; r < 4; ++r) {
            float mp = minpos[m][r], mn = maxneg[m][r];
            #pragma unroll
            for (int off = 1; off < 16; off <<= 1) {
                mp = fminf(mp, __shfl_xor(mp, off));
                mn = fmaxf(mn, __shfl_xor(mn, off));
            }
            if (llo == 0) {
                const int row = R + m * 16 + lhi * 4 + r;
                ppos[(size_t)chnk * B + row] = mp;
                pneg[(size_t)chnk * B + row] = mn;
            }
        }
}

__global__ void mmcl_final_kernel(const float* __restrict__ sqn,
                                  const float* __restrict__ ppos,
                                  const float* __restrict__ pneg,
                                  float* __restrict__ out)
{
    const int row = blockIdx.x * 256 + threadIdx.x;
    float mp = INFINITY, mn = -INFINITY;
    #pragma unroll
    for (int c = 0; c < NCHUNK; ++c) {
        mp = fminf(mp, ppos[(size_t)c * B + row]);
        mn = fmaxf(mn, pneg[(size_t)c * B + row]);
    }
    const float sq  = sqn[row];
    const float pos = isinf(mp) ? INFINITY : sqrtf(fmaxf(sq + mp, 0.f));
    const float neg = (mn == -INFINITY) ? -INFINITY : sqrtf(fmaxf(sq + mn, 0.f));
    const float term = fmaxf(pos - neg + MARGIN, 0.f);

    float s = term;
    #pragma unroll
    for (int off = 32; off; off >>= 1) s += __shfl_down(s, off);
    __shared__ float wsum[4];
    const int wave = threadIdx.x >> 6, lane = threadIdx.x & 63;
    if (lane == 0) wsum[wave] = s;
    __syncthreads();
    if (threadIdx.x == 0)
        atomicAdd(out, (wsum[0] + wsum[1] + wsum[2] + wsum[3]) * (1.0f / B));
}

extern "C" void kernel_launch(void* const* d_in, const int* in_sizes, int n_in,
                              void* d_out, int out_size, void* d_ws, size_t ws_size,
                              hipStream_t stream) {
    (void)in_sizes; (void)n_in; (void)out_size; (void)ws_size;
    const float* X   = (const float*)d_in[0];
    const int*   lab = (const int*)d_in[1];
    float* out = (float*)d_out;

    float*  sqn  = (float*)d_ws;
    float*  ppos = sqn + B;
    float*  pneg = ppos + (size_t)NCHUNK * B;
    ushort* Xh   = (ushort*)(pneg + (size_t)NCHUNK * B);

    mmcl_prep_kernel<<<(B * 16) / 256, 256, 0, stream>>>(X, Xh, sqn, out);
    mmcl_mfma_kernel<<<dim3(B / RPB, NCHUNK), 256, 0, stream>>>(Xh, sqn, lab, ppos, pneg);
    mmcl_final_kernel<<<B / 256, 256, 0, stream>>>(sqn, ppos, pneg, out);
}